// Round 5
// baseline (14355.728 us; speedup 1.0000x reference)
//
#include <hip/hip_runtime.h>
#include <hip/hip_bf16.h>
#include <math.h>
#include <stdint.h>

#define NLAYERS 30
#define BB 16
#define LL 32768
#define TL 64

#define XS 16384.0f   // x fixed-point scale (range +-2)
#define XSI (1.0f / 16384.0f)
#define US 32767.0f   // u scale (|u|<1)
#define USI (1.0f / 32767.0f)
#define SS 16384.0f   // skip scale (range +-2)
#define SSI (1.0f / 16384.0f)

// ---------------- embedding MLP: t[b,512] ----------------
__global__ void emb_kernel(const int* __restrict__ step, const float* __restrict__ emb,
                           const float* __restrict__ W1, const float* __restrict__ b1,
                           const float* __restrict__ W2, const float* __restrict__ b2,
                           float* __restrict__ t_out) {
    int b = blockIdx.x, j = threadIdx.x;
    __shared__ float e[128];
    __shared__ float t1[512];
    int s = step[b];
    if (j < 128) e[j] = emb[s * 128 + j];
    __syncthreads();
    float acc = b1[j];
    const float* w = W1 + j * 128;
    for (int k = 0; k < 128; ++k) acc += w[k] * e[k];
    t1[j] = acc / (1.f + __expf(-acc));
    __syncthreads();
    float acc2 = b2[j];
    const float* w2 = W2 + j * 512;
    for (int k = 0; k < 512; ++k) acc2 += w2[k] * t1[k];
    t_out[b * 512 + j] = acc2 / (1.f + __expf(-acc2));
}

// ---------------- dp[i,b,c] = t[b] . diff_W[i,c,:] + diff_b[i,c] ----------------
__global__ void dp_kernel(const float* __restrict__ t, const float* __restrict__ diff_W,
                          const float* __restrict__ diff_b, float* __restrict__ dp) {
    int i = blockIdx.x, b = blockIdx.y, c = threadIdx.x;  // 64 threads
    __shared__ float ts[512];
    for (int k = c; k < 512; k += 64) ts[k] = t[b * 512 + k];
    __syncthreads();
    const float* w = diff_W + (size_t)(i * 64 + c) * 512;
    float acc = diff_b[i * 64 + c];
    for (int k = 0; k < 512; ++k) acc += w[k] * ts[k];
    dp[(i * BB + b) * 64 + c] = acc;
}

// ---------------- weight transposes ----------------
__global__ void transpose_w_kernel(const float* __restrict__ dconv_W, float* __restrict__ wT,
                                   const float* __restrict__ out_W, float* __restrict__ oT,
                                   const float* __restrict__ Wo1, float* __restrict__ Wo1T) {
    int idx = blockIdx.x * 256 + threadIdx.x;
    if (idx < 30 * 64 * 3 * 128) {
        int o = idx & 127;
        int tap = (idx >> 7) % 3;
        int c = (idx / (128 * 3)) & 63;
        int i = idx / (128 * 3 * 64);
        wT[idx] = dconv_W[((size_t)(i * 128 + o) * 64 + c) * 3 + tap];
    }
    if (idx < 30 * 64 * 128) {
        int o = idx & 127;
        int c = (idx >> 7) & 63;
        int i = idx >> 13;
        oT[idx] = out_W[(size_t)(i * 128 + o) * 64 + c];
    }
    if (idx < 64 * 64) {
        int o = idx & 63, c = idx >> 6;
        Wo1T[idx] = Wo1[o * 64 + c];
    }
}

// ---------------- input projection x = relu(audio*Win + bin), int16 ----------------
__global__ void inproj_kernel(const float* __restrict__ audio, const float* __restrict__ Win,
                              const float* __restrict__ bin_, int16_t* __restrict__ x) {
    size_t idx = (size_t)blockIdx.x * 256 + threadIdx.x;  // over B*64*L
    int l = (int)(idx & (LL - 1));
    int c = (int)((idx >> 15) & 63);
    int b = (int)(idx >> 21);
    float v = audio[(size_t)b * LL + l] * Win[c] + bin_[c];
    v = v > 0.f ? v : 0.f;
    v = fminf(v, 1.999f);
    x[idx] = (int16_t)__float2int_rn(v * XS);
}

// ---------------- layer part A: dilated conv + gated activation -> U int16 ----------------
__global__ __launch_bounds__(512, 1) void convA_kernel(
    const int16_t* __restrict__ xin, int16_t* __restrict__ U,
    const float* __restrict__ dp,       // [B][64]  this layer
    const float* __restrict__ wT,       // [64][3][128] this layer
    const float* __restrict__ dconv_b,  // [128]
    int d) {
    __shared__ float sxm[64][TL];
    __shared__ float sx0[64][TL];
    __shared__ float sxp[64][TL];
    __shared__ float sdp[64];

    const int b = blockIdx.y;
    const int l0 = blockIdx.x * TL;
    const int tid = threadIdx.x;
    const int lane = tid & 63;
    const int g = tid >> 6;  // 0..7, wave-uniform

    if (tid < 64) sdp[tid] = dp[b * 64 + tid];
    __syncthreads();

    #pragma unroll
    for (int it = 0; it < 8; ++it) {
        int c = g * 8 + it;
        float dpv = sdp[c];
        int pm = l0 + lane - d;
        int pp = l0 + lane + d;
        const int16_t* xb = xin + (size_t)(b * 64 + c) * LL;
        sxm[c][lane] = (pm >= 0) ? (float)xb[pm] * XSI + dpv : 0.f;
        sx0[c][lane] = (float)xb[l0 + lane] * XSI + dpv;
        sxp[c][lane] = (pp < LL) ? (float)xb[pp] * XSI + dpv : 0.f;
    }
    __syncthreads();

    const int o0 = g * 8;
    const int o0s = __builtin_amdgcn_readfirstlane(o0);
    float lo[8], hi[8];
    #pragma unroll
    for (int j = 0; j < 8; ++j) {
        lo[j] = dconv_b[o0s + j];
        hi[j] = dconv_b[64 + o0s + j];
    }
    for (int c = 0; c < 64; ++c) {
        float xm = sxm[c][lane], x0v = sx0[c][lane], xp = sxp[c][lane];
        const float* w = wT + c * 384;
        #pragma unroll
        for (int j = 0; j < 8; ++j) {
            lo[j] += w[o0s + j] * xm + w[128 + o0s + j] * x0v + w[256 + o0s + j] * xp;
            hi[j] += w[64 + o0s + j] * xm + w[192 + o0s + j] * x0v + w[320 + o0s + j] * xp;
        }
    }
    #pragma unroll
    for (int j = 0; j < 8; ++j) {
        float tv = tanhf(lo[j]);
        float sv = 1.f / (1.f + __expf(-hi[j]));
        float u = tv * sv;  // in (-1, 1)
        U[(size_t)(b * 64 + o0 + j) * LL + l0 + lane] = (int16_t)__float2int_rn(u * US);
    }
}

// ---------------- layer part B: z = out_W . u ; x in-place update; skip += ----------------
__global__ __launch_bounds__(512, 1) void projB_kernel(
    int16_t* __restrict__ x, int16_t* __restrict__ skip,
    const int16_t* __restrict__ U, const float* __restrict__ oT,  // [64][128] this layer
    const float* __restrict__ out_b) {                            // [128]
    __shared__ float su[64][TL];
    const int b = blockIdx.y;
    const int l0 = blockIdx.x * TL;
    const int tid = threadIdx.x;
    const int lane = tid & 63;
    const int g = tid >> 6;

    #pragma unroll
    for (int it = 0; it < 8; ++it) {
        int c = it * 8 + g;
        su[c][lane] = (float)U[(size_t)(b * 64 + c) * LL + l0 + lane] * USI;
    }
    __syncthreads();

    const int z0 = g * 16;
    const int z0s = __builtin_amdgcn_readfirstlane(z0);
    float z[16];
    #pragma unroll
    for (int j = 0; j < 16; ++j) z[j] = out_b[z0s + j];
    for (int c = 0; c < 64; ++c) {
        float uv = su[c][lane];
        const float* ow = oT + c * 128;
        #pragma unroll
        for (int j = 0; j < 16; ++j) z[j] += ow[z0s + j] * uv;
    }
    const float inv_s2 = 0.70710678118654752440f;
    if (z0s < 64) {
        #pragma unroll
        for (int j = 0; j < 16; ++j) {
            size_t idx = (size_t)(b * 64 + z0 + j) * LL + l0 + lane;
            float v = ((float)x[idx] * XSI + z[j]) * inv_s2;
            v = fminf(fmaxf(v, -1.999f), 1.999f);
            x[idx] = (int16_t)__float2int_rn(v * XS);
        }
    } else {
        #pragma unroll
        for (int j = 0; j < 16; ++j) {
            size_t idx = (size_t)(b * 64 + z0 - 64 + j) * LL + l0 + lane;
            float v = (float)skip[idx] * SSI + z[j];
            v = fminf(fmaxf(v, -1.999f), 1.999f);
            skip[idx] = (int16_t)__float2int_rn(v * SS);
        }
    }
}

// ---------------- output head ----------------
__global__ __launch_bounds__(256) void head_kernel(const int16_t* __restrict__ skip,
                                                   const float* __restrict__ Wo1T,
                                                   const float* __restrict__ bo1,
                                                   const float* __restrict__ Wo2,
                                                   const float* __restrict__ bo2,
                                                   float* __restrict__ out) {
    size_t idx = (size_t)blockIdx.x * 256 + threadIdx.x;  // B*L
    int l = (int)(idx & (LL - 1));
    int b = (int)(idx >> 15);
    const float inv30 = 0.18257418583505537115f;  // 1/sqrt(30)
    float h[64];
    #pragma unroll
    for (int o = 0; o < 64; ++o) h[o] = bo1[o];
    for (int c = 0; c < 64; ++c) {
        size_t si = ((size_t)b * 64 + c) * LL + l;
        float s = (float)skip[si] * SSI * inv30;
        const float* w = Wo1T + c * 64;
        #pragma unroll
        for (int o = 0; o < 64; ++o) h[o] += w[o] * s;
    }
    float acc = bo2[0];
    #pragma unroll
    for (int c = 0; c < 64; ++c) acc += (h[c] > 0.f ? h[c] : 0.f) * Wo2[c];
    out[idx] = acc;
}

extern "C" void kernel_launch(void* const* d_in, const int* in_sizes, int n_in,
                              void* d_out, int out_size, void* d_ws, size_t ws_size,
                              hipStream_t stream) {
    const float* audio = (const float*)d_in[0];
    const int* dstep = (const int*)d_in[1];
    const float* emb = (const float*)d_in[2];
    const float* W1 = (const float*)d_in[3];
    const float* b1 = (const float*)d_in[4];
    const float* W2 = (const float*)d_in[5];
    const float* b2 = (const float*)d_in[6];
    const float* Win = (const float*)d_in[7];
    const float* bin_ = (const float*)d_in[8];
    const float* diff_W = (const float*)d_in[9];
    const float* diff_b = (const float*)d_in[10];
    const float* dconv_W = (const float*)d_in[11];
    const float* dconv_b = (const float*)d_in[12];
    const float* out_W = (const float*)d_in[13];
    const float* out_b = (const float*)d_in[14];
    const float* Wo1 = (const float*)d_in[15];
    const float* bo1 = (const float*)d_in[16];
    const float* Wo2 = (const float*)d_in[17];
    const float* bo2 = (const float*)d_in[18];

    const size_t NACT = (size_t)BB * 64 * LL;  // 33,554,432 elements

    // Layout (all int16 activations): x(64MiB) + skip(64MiB) + U(64MiB) + params(~4MiB) = 196 MiB
    uint8_t* p = (uint8_t*)d_ws;
    int16_t* x = (int16_t*)p;        p += NACT * 2;
    int16_t* skip = (int16_t*)p;     p += NACT * 2;
    int16_t* U = (int16_t*)p;        p += NACT * 2;
    float* t = (float*)p;            p += 8192 * 4;
    float* dp = (float*)p;           p += 30720 * 4;
    float* wT = (float*)p;           p += 737280 * 4;
    float* oT = (float*)p;           p += 245760 * 4;
    float* Wo1T = (float*)p;         p += 4096 * 4;

    hipMemsetAsync(skip, 0, NACT * 2, stream);
    emb_kernel<<<BB, 512, 0, stream>>>(dstep, emb, W1, b1, W2, b2, t);
    dp_kernel<<<dim3(NLAYERS, BB), 64, 0, stream>>>(t, diff_W, diff_b, dp);
    transpose_w_kernel<<<2880, 256, 0, stream>>>(dconv_W, wT, out_W, oT, Wo1, Wo1T);
    inproj_kernel<<<131072, 256, 0, stream>>>(audio, Win, bin_, x);

    dim3 lgrid(LL / TL, BB);
    for (int i = 0; i < NLAYERS; ++i) {
        int d = 1 << (i % 10);
        convA_kernel<<<lgrid, 512, 0, stream>>>(
            x, U, dp + (size_t)i * BB * 64, wT + (size_t)i * 64 * 3 * 128,
            dconv_b + i * 128, d);
        projB_kernel<<<lgrid, 512, 0, stream>>>(
            x, skip, U, oT + (size_t)i * 64 * 128, out_b + i * 128);
    }
    head_kernel<<<(BB * LL) / 256, 256, 0, stream>>>(skip, Wo1T, bo1, Wo2, bo2, (float*)d_out);
}

// Round 6
// 5702.938 us; speedup vs baseline: 2.5173x; 2.5173x over previous
//
#include <hip/hip_runtime.h>
#include <hip/hip_bf16.h>
#include <math.h>
#include <stdint.h>

#define NLAYERS 30
#define BB 16
#define LL 32768

#define SS 16384.0f
#define SSI (1.0f / 16384.0f)

typedef __attribute__((ext_vector_type(8))) short bf16x8;
typedef __attribute__((ext_vector_type(4))) float f32x4;

__device__ inline float bf2f(ushort u) {
    union { uint i; float f; } v; v.i = ((uint)u) << 16; return v.f;
}
__device__ inline ushort f2bf(float f) {  // RNE
    uint u = __float_as_uint(f);
    return (ushort)((u + 0x7FFFu + ((u >> 16) & 1u)) >> 16);
}

// ---------------- embedding MLP: t[b,512] ----------------
__global__ void emb_kernel(const int* __restrict__ step, const float* __restrict__ emb,
                           const float* __restrict__ W1, const float* __restrict__ b1,
                           const float* __restrict__ W2, const float* __restrict__ b2,
                           float* __restrict__ t_out) {
    int b = blockIdx.x, j = threadIdx.x;
    __shared__ float e[128];
    __shared__ float t1[512];
    int s = step[b];
    if (j < 128) e[j] = emb[s * 128 + j];
    __syncthreads();
    float acc = b1[j];
    const float* w = W1 + j * 128;
    for (int k = 0; k < 128; ++k) acc += w[k] * e[k];
    t1[j] = acc / (1.f + __expf(-acc));
    __syncthreads();
    float acc2 = b2[j];
    const float* w2 = W2 + j * 512;
    for (int k = 0; k < 512; ++k) acc2 += w2[k] * t1[k];
    t_out[b * 512 + j] = acc2 / (1.f + __expf(-acc2));
}

// ---------------- dp[i,b,c] = t[b] . diff_W[i,c,:] + diff_b[i,c] ----------------
__global__ void dp_kernel(const float* __restrict__ t, const float* __restrict__ diff_W,
                          const float* __restrict__ diff_b, float* __restrict__ dp) {
    int i = blockIdx.x, b = blockIdx.y, c = threadIdx.x;  // 64 threads
    __shared__ float ts[512];
    for (int k = c; k < 512; k += 64) ts[k] = t[b * 512 + k];
    __syncthreads();
    const float* w = diff_W + (size_t)(i * 64 + c) * 512;
    float acc = diff_b[i * 64 + c];
    for (int k = 0; k < 512; ++k) acc += w[k] * ts[k];
    dp[(i * BB + b) * 64 + c] = acc;
}

// ---------------- weight shuffles into MFMA fragment order (bf16) ----------------
// wB[i][mt][s][lane][8]: A-frag for conv GEMM. o = mt*16+(lane&15); tap=s>>1; c=(s&1)*32+(lane>>4)*8+j
// oB[i][mt][s][lane][8]: A-frag for out-proj. o = mt*16+(lane&15); c=s*32+(lane>>4)*8+j
__global__ void prep_w_kernel(const float* __restrict__ dconv_W, ushort* __restrict__ wB,
                              const float* __restrict__ out_W, ushort* __restrict__ oB,
                              const float* __restrict__ Wo1, float* __restrict__ Wo1T) {
    int idx = blockIdx.x * 256 + threadIdx.x;
    if (idx < 30 * 8 * 6 * 512) {
        int i = idx / 24576;
        int r = idx % 24576;
        int mt = r / 3072;
        int s = (r / 512) % 6;
        int lane = (r >> 3) & 63;
        int j = r & 7;
        int o = mt * 16 + (lane & 15);
        int tap = s >> 1;
        int c = (s & 1) * 32 + (lane >> 4) * 8 + j;
        wB[idx] = f2bf(dconv_W[((size_t)(i * 128 + o) * 64 + c) * 3 + tap]);
    }
    if (idx < 30 * 8 * 2 * 512) {
        int i = idx / 8192;
        int r = idx % 8192;
        int mt = r / 1024;
        int s = (r / 512) % 2;
        int lane = (r >> 3) & 63;
        int j = r & 7;
        int o = mt * 16 + (lane & 15);
        int c = s * 32 + (lane >> 4) * 8 + j;
        oB[idx] = f2bf(out_W[(size_t)(i * 128 + o) * 64 + c]);
    }
    if (idx < 4096) {
        int o = idx & 63, c = idx >> 6;
        Wo1T[idx] = Wo1[o * 64 + c];
    }
}

// ---------------- bias3[i][b][{full,left,right}][128]: dp folded through conv weights ----------------
__global__ void bias3_kernel(const float* __restrict__ dp, const float* __restrict__ dconv_W,
                             const float* __restrict__ dconv_b, float* __restrict__ bias3) {
    int i = blockIdx.x, b = blockIdx.y, o = threadIdx.x;  // 128 threads
    __shared__ float sdp[64];
    if (o < 64) sdp[o] = dp[(i * BB + b) * 64 + o];
    __syncthreads();
    const float* wrow = dconv_W + (size_t)(i * 128 + o) * 192;
    float f = 0.f, lft = 0.f, rgt = 0.f;
    for (int c = 0; c < 64; ++c) {
        float w0 = wrow[c * 3 + 0], w1 = wrow[c * 3 + 1], w2 = wrow[c * 3 + 2];
        float dv = sdp[c];
        f += dv * (w0 + w1 + w2);
        lft += dv * w0;
        rgt += dv * w2;
    }
    float* dst = bias3 + (size_t)(i * BB + b) * 384;
    dst[o] = f + dconv_b[i * 128 + o];
    dst[128 + o] = lft;
    dst[256 + o] = rgt;
}

// ---------------- input projection -> x[b][l][c] bf16 ----------------
__global__ void inproj_kernel(const float* __restrict__ audio, const float* __restrict__ Win,
                              const float* __restrict__ bin_, ushort* __restrict__ x) {
    int idx = blockIdx.x * 256 + threadIdx.x;  // B*L*8
    int c8 = idx & 7;
    int l = (idx >> 3) & (LL - 1);
    int b = idx >> 18;
    float a = audio[(size_t)b * LL + l];
    ushort us[8];
    #pragma unroll
    for (int cc = 0; cc < 8; ++cc) {
        int c = c8 * 8 + cc;
        float v = a * Win[c] + bin_[c];
        us[cc] = f2bf(v > 0.f ? v : 0.f);
    }
    ushort4* dst = (ushort4*)(x + ((size_t)b * LL + l) * 64 + c8 * 8);
    dst[0] = make_ushort4(us[0], us[1], us[2], us[3]);
    dst[1] = make_ushort4(us[4], us[5], us[6], us[7]);
}

// ---------------- conv layer (MFMA): U = gate(W*x + bias3) ----------------
__global__ __launch_bounds__(256, 4) void convA_mfma(
    const ushort* __restrict__ x, ushort* __restrict__ U,
    const ushort* __restrict__ wB,    // [8][6][64][8] this layer
    const float* __restrict__ bias3,  // [16][3][128] this layer
    int d) {
    const int b = blockIdx.y;
    const int seg = blockIdx.x;  // 512-pos segment
    const int tid = threadIdx.x;
    const int lane = tid & 63;
    const int p = tid >> 6;  // wave = mtile pair (p: lo rows 16p.., p+4: hi rows 64+16p..)
    const int n = lane & 15;
    const int kg = lane >> 4;
    const int rlo = p * 16 + kg * 4;

    bf16x8 A0[6], A1[6];
    #pragma unroll
    for (int s = 0; s < 6; ++s) {
        A0[s] = *(const bf16x8*)(wB + ((size_t)(p * 6 + s) * 64 + lane) * 8);
        A1[s] = *(const bf16x8*)(wB + ((size_t)((p + 4) * 6 + s) * 64 + lane) * 8);
    }
    const float* bb = bias3 + (size_t)b * 384;
    f32x4 bF_lo = *(const f32x4*)(bb + rlo);
    f32x4 bF_hi = *(const f32x4*)(bb + 64 + rlo);
    f32x4 bL_lo = *(const f32x4*)(bb + 128 + rlo);
    f32x4 bL_hi = *(const f32x4*)(bb + 192 + rlo);
    f32x4 bR_lo = *(const f32x4*)(bb + 256 + rlo);
    f32x4 bR_hi = *(const f32x4*)(bb + 320 + rlo);

    const ushort* xb = x + (size_t)b * LL * 64;
    ushort* Ub = U + (size_t)b * LL * 64;

    for (int t = 0; t < 32; ++t) {
        const int l0 = seg * 512 + t * 16;
        bf16x8 Bf[6];
        #pragma unroll
        for (int tap = 0; tap < 3; ++tap) {
            int lx = l0 + n + (tap - 1) * d;
            bool v = (lx >= 0) && (lx < LL);
            #pragma unroll
            for (int h = 0; h < 2; ++h) {
                bf16x8 bv = {0, 0, 0, 0, 0, 0, 0, 0};
                if (v) bv = *(const bf16x8*)(xb + (size_t)lx * 64 + h * 32 + kg * 8);
                Bf[tap * 2 + h] = bv;
            }
        }
        f32x4 accL = {0.f, 0.f, 0.f, 0.f}, accH = {0.f, 0.f, 0.f, 0.f};
        #pragma unroll
        for (int s = 0; s < 6; ++s) {
            accL = __builtin_amdgcn_mfma_f32_16x16x32_bf16(A0[s], Bf[s], accL, 0, 0, 0);
            accH = __builtin_amdgcn_mfma_f32_16x16x32_bf16(A1[s], Bf[s], accH, 0, 0, 0);
        }
        int lx0 = l0 + n;
        float selL = (lx0 < d) ? 1.f : 0.f;
        float selR = (lx0 >= LL - d) ? 1.f : 0.f;
        ushort4 uv;
        #pragma unroll
        for (int j = 0; j < 4; ++j) {
            float lo = accL[j] + bF_lo[j] - selL * bL_lo[j] - selR * bR_lo[j];
            float hi = accH[j] + bF_hi[j] - selL * bL_hi[j] - selR * bR_hi[j];
            float tv = 1.f - 2.f / (1.f + __expf(2.f * lo));
            float sv = 1.f / (1.f + __expf(-hi));
            ushort uq = f2bf(tv * sv);
            if (j == 0) uv.x = uq;
            if (j == 1) uv.y = uq;
            if (j == 2) uv.z = uq;
            if (j == 3) uv.w = uq;
        }
        *(ushort4*)(Ub + (size_t)lx0 * 64 + rlo) = uv;
    }
}

// ---------------- out-proj layer (MFMA): z = oW*U; x=(x+z)/sqrt2; skip+=z ----------------
__global__ __launch_bounds__(256, 4) void projB_mfma(
    ushort* __restrict__ x, int16_t* __restrict__ skip,
    const ushort* __restrict__ U,
    const ushort* __restrict__ oB,     // [8][2][64][8] this layer
    const float* __restrict__ out_b) { // [128]
    const int b = blockIdx.y;
    const int seg = blockIdx.x;
    const int tid = threadIdx.x;
    const int lane = tid & 63;
    const int p = tid >> 6;
    const int n = lane & 15;
    const int kg = lane >> 4;
    const int rlo = p * 16 + kg * 4;

    bf16x8 A0[2], A1[2];
    #pragma unroll
    for (int s = 0; s < 2; ++s) {
        A0[s] = *(const bf16x8*)(oB + ((size_t)(p * 2 + s) * 64 + lane) * 8);
        A1[s] = *(const bf16x8*)(oB + ((size_t)((p + 4) * 2 + s) * 64 + lane) * 8);
    }
    f32x4 obL = *(const f32x4*)(out_b + rlo);
    f32x4 obH = *(const f32x4*)(out_b + 64 + rlo);

    const ushort* Ub = U + (size_t)b * LL * 64;
    ushort* xb = x + (size_t)b * LL * 64;
    int16_t* sb = skip + (size_t)b * LL * 64;
    const float inv_s2 = 0.70710678118654752440f;

    for (int t = 0; t < 32; ++t) {
        const int l0 = seg * 512 + t * 16;
        bf16x8 Bf[2];
        #pragma unroll
        for (int s = 0; s < 2; ++s)
            Bf[s] = *(const bf16x8*)(Ub + (size_t)(l0 + n) * 64 + s * 32 + kg * 8);
        f32x4 accL = {0.f, 0.f, 0.f, 0.f}, accH = {0.f, 0.f, 0.f, 0.f};
        #pragma unroll
        for (int s = 0; s < 2; ++s) {
            accL = __builtin_amdgcn_mfma_f32_16x16x32_bf16(A0[s], Bf[s], accL, 0, 0, 0);
            accH = __builtin_amdgcn_mfma_f32_16x16x32_bf16(A1[s], Bf[s], accH, 0, 0, 0);
        }
        size_t off = (size_t)(l0 + n) * 64 + rlo;
        ushort4 xo = *(const ushort4*)(xb + off);
        ushort4 xn;
        xn.x = f2bf((bf2f(xo.x) + accL[0] + obL[0]) * inv_s2);
        xn.y = f2bf((bf2f(xo.y) + accL[1] + obL[1]) * inv_s2);
        xn.z = f2bf((bf2f(xo.z) + accL[2] + obL[2]) * inv_s2);
        xn.w = f2bf((bf2f(xo.w) + accL[3] + obL[3]) * inv_s2);
        *(ushort4*)(xb + off) = xn;
        short4 so = *(const short4*)(sb + off);
        short4 sn;
        float v;
        v = fminf(fmaxf((float)so.x * SSI + accH[0] + obH[0], -1.999f), 1.999f);
        sn.x = (short)__float2int_rn(v * SS);
        v = fminf(fmaxf((float)so.y * SSI + accH[1] + obH[1], -1.999f), 1.999f);
        sn.y = (short)__float2int_rn(v * SS);
        v = fminf(fmaxf((float)so.z * SSI + accH[2] + obH[2], -1.999f), 1.999f);
        sn.z = (short)__float2int_rn(v * SS);
        v = fminf(fmaxf((float)so.w * SSI + accH[3] + obH[3], -1.999f), 1.999f);
        *(short4*)(sb + off) = sn, sn.w = (short)__float2int_rn(v * SS), *(short4*)(sb + off) = sn;
    }
}

// ---------------- output head ----------------
__global__ __launch_bounds__(256) void head_kernel(const int16_t* __restrict__ skip,
                                                   const float* __restrict__ Wo1T,
                                                   const float* __restrict__ bo1,
                                                   const float* __restrict__ Wo2,
                                                   const float* __restrict__ bo2,
                                                   float* __restrict__ out) {
    size_t idx = (size_t)blockIdx.x * 256 + threadIdx.x;  // B*L
    const float inv30 = 0.18257418583505537115f;          // 1/sqrt(30)
    float h[64];
    #pragma unroll
    for (int o = 0; o < 64; ++o) h[o] = bo1[o];
    const int16_t* sp = skip + idx * 64;
    for (int c = 0; c < 64; ++c) {
        float s = (float)sp[c] * SSI * inv30;
        const float* w = Wo1T + c * 64;
        #pragma unroll
        for (int o = 0; o < 64; ++o) h[o] += w[o] * s;
    }
    float acc = bo2[0];
    #pragma unroll
    for (int c = 0; c < 64; ++c) acc += (h[c] > 0.f ? h[c] : 0.f) * Wo2[c];
    out[idx] = acc;
}

extern "C" void kernel_launch(void* const* d_in, const int* in_sizes, int n_in,
                              void* d_out, int out_size, void* d_ws, size_t ws_size,
                              hipStream_t stream) {
    const float* audio = (const float*)d_in[0];
    const int* dstep = (const int*)d_in[1];
    const float* emb = (const float*)d_in[2];
    const float* W1 = (const float*)d_in[3];
    const float* b1 = (const float*)d_in[4];
    const float* W2 = (const float*)d_in[5];
    const float* b2 = (const float*)d_in[6];
    const float* Win = (const float*)d_in[7];
    const float* bin_ = (const float*)d_in[8];
    const float* diff_W = (const float*)d_in[9];
    const float* diff_b = (const float*)d_in[10];
    const float* dconv_W = (const float*)d_in[11];
    const float* dconv_b = (const float*)d_in[12];
    const float* out_W = (const float*)d_in[13];
    const float* out_b = (const float*)d_in[14];
    const float* Wo1 = (const float*)d_in[15];
    const float* bo1 = (const float*)d_in[16];
    const float* Wo2 = (const float*)d_in[17];
    const float* bo2 = (const float*)d_in[18];

    const size_t NACT = (size_t)BB * LL * 64;  // 33,554,432 elements

    uint8_t* p = (uint8_t*)d_ws;
    ushort* x = (ushort*)p;      p += NACT * 2;   // bf16 [b][l][c]
    int16_t* skip = (int16_t*)p; p += NACT * 2;   // int16 [b][l][c]
    ushort* U = (ushort*)p;      p += NACT * 2;   // bf16 [b][l][c]
    float* t = (float*)p;        p += 8192 * 4;
    float* dp = (float*)p;       p += 30720 * 4;
    ushort* wB = (ushort*)p;     p += 737280 * 2;
    ushort* oB = (ushort*)p;     p += 245760 * 2;
    float* bias3 = (float*)p;    p += 184320 * 4;
    float* Wo1T = (float*)p;     p += 4096 * 4;

    hipMemsetAsync(skip, 0, NACT * 2, stream);
    emb_kernel<<<BB, 512, 0, stream>>>(dstep, emb, W1, b1, W2, b2, t);
    dp_kernel<<<dim3(NLAYERS, BB), 64, 0, stream>>>(t, diff_W, diff_b, dp);
    prep_w_kernel<<<2880, 256, 0, stream>>>(dconv_W, wB, out_W, oB, Wo1, Wo1T);
    bias3_kernel<<<dim3(NLAYERS, BB), 128, 0, stream>>>(dp, dconv_W, dconv_b, bias3);
    inproj_kernel<<<16384, 256, 0, stream>>>(audio, Win, bin_, x);

    dim3 lgrid(LL / 512, BB);
    for (int i = 0; i < NLAYERS; ++i) {
        int d = 1 << (i % 10);
        convA_mfma<<<lgrid, 256, 0, stream>>>(
            x, U, wB + (size_t)i * 24576, bias3 + (size_t)i * BB * 384, d);
        projB_mfma<<<lgrid, 256, 0, stream>>>(
            x, skip, U, oB + (size_t)i * 8192, out_b + i * 128);
    }
    head_kernel<<<(BB * LL) / 256, 256, 0, stream>>>(skip, Wo1T, bo1, Wo2, bo2, (float*)d_out);
}

// Round 7
// 5272.374 us; speedup vs baseline: 2.7228x; 1.0817x over previous
//
#include <hip/hip_runtime.h>
#include <hip/hip_bf16.h>
#include <math.h>
#include <stdint.h>

#define NLAYERS 30
#define BB 16
#define LL 32768

#define SS 16384.0f
#define SSI (1.0f / 16384.0f)

typedef __attribute__((ext_vector_type(8))) short bf16x8;
typedef __attribute__((ext_vector_type(8))) short s16x8;
typedef __attribute__((ext_vector_type(4))) float f32x4;

__device__ inline float bf2f(ushort u) {
    union { uint i; float f; } v; v.i = ((uint)u) << 16; return v.f;
}
__device__ inline ushort f2bf(float f) {  // RNE
    uint u = __float_as_uint(f);
    return (ushort)((u + 0x7FFFu + ((u >> 16) & 1u)) >> 16);
}

// ---------------- embedding MLP: t[b,512] ----------------
__global__ void emb_kernel(const int* __restrict__ step, const float* __restrict__ emb,
                           const float* __restrict__ W1, const float* __restrict__ b1,
                           const float* __restrict__ W2, const float* __restrict__ b2,
                           float* __restrict__ t_out) {
    int b = blockIdx.x, j = threadIdx.x;
    __shared__ float e[128];
    __shared__ float t1[512];
    int s = step[b];
    if (j < 128) e[j] = emb[s * 128 + j];
    __syncthreads();
    float acc = b1[j];
    const float* w = W1 + j * 128;
    for (int k = 0; k < 128; ++k) acc += w[k] * e[k];
    t1[j] = acc / (1.f + __expf(-acc));
    __syncthreads();
    float acc2 = b2[j];
    const float* w2 = W2 + j * 512;
    for (int k = 0; k < 512; ++k) acc2 += w2[k] * t1[k];
    t_out[b * 512 + j] = acc2 / (1.f + __expf(-acc2));
}

// ---------------- dp[i,b,c] = t[b] . diff_W[i,c,:] + diff_b[i,c] ----------------
__global__ void dp_kernel(const float* __restrict__ t, const float* __restrict__ diff_W,
                          const float* __restrict__ diff_b, float* __restrict__ dp) {
    int i = blockIdx.x, b = blockIdx.y, c = threadIdx.x;  // 64 threads
    __shared__ float ts[512];
    for (int k = c; k < 512; k += 64) ts[k] = t[b * 512 + k];
    __syncthreads();
    const float* w = diff_W + (size_t)(i * 64 + c) * 512;
    float acc = diff_b[i * 64 + c];
    for (int k = 0; k < 512; ++k) acc += w[k] * ts[k];
    dp[(i * BB + b) * 64 + c] = acc;
}

// ---------------- weight shuffles into MFMA fragment order (bf16) ----------------
// wB[i][mt][s][lane][8]: conv A-frag. o = mt*16+(lane&15); tap=s>>1; c=(s&1)*32+(lane>>4)*8+j
// oB[i][mt][s][lane][8]: proj A-frag. o = mt*16+(lane&15); c=s*32+(lane>>4)*8+j
// Wo1B[mt][s][lane][8]:  head A-frag, scaled by SSI/sqrt(30). o = mt*16+(lane&15) (o<64)
__global__ void prep_w_kernel(const float* __restrict__ dconv_W, ushort* __restrict__ wB,
                              const float* __restrict__ out_W, ushort* __restrict__ oB,
                              const float* __restrict__ Wo1, ushort* __restrict__ Wo1B) {
    int idx = blockIdx.x * 256 + threadIdx.x;
    if (idx < 30 * 8 * 6 * 512) {
        int i = idx / 24576;
        int r = idx % 24576;
        int mt = r / 3072;
        int s = (r / 512) % 6;
        int lane = (r >> 3) & 63;
        int j = r & 7;
        int o = mt * 16 + (lane & 15);
        int tap = s >> 1;
        int c = (s & 1) * 32 + (lane >> 4) * 8 + j;
        wB[idx] = f2bf(dconv_W[((size_t)(i * 128 + o) * 64 + c) * 3 + tap]);
    }
    if (idx < 30 * 8 * 2 * 512) {
        int i = idx / 8192;
        int r = idx % 8192;
        int mt = r / 1024;
        int s = (r / 512) % 2;
        int lane = (r >> 3) & 63;
        int j = r & 7;
        int o = mt * 16 + (lane & 15);
        int c = s * 32 + (lane >> 4) * 8 + j;
        oB[idx] = f2bf(out_W[(size_t)(i * 128 + o) * 64 + c]);
    }
    if (idx < 4 * 2 * 512) {
        int mt = idx / 1024;
        int s = (idx / 512) % 2;
        int lane = (idx >> 3) & 63;
        int j = idx & 7;
        int o = mt * 16 + (lane & 15);
        int c = s * 32 + (lane >> 4) * 8 + j;
        const float hscale = SSI * 0.18257418583505537115f;  // SSI / sqrt(30)
        Wo1B[idx] = f2bf(Wo1[o * 64 + c] * hscale);
    }
}

// ---------------- bias3[i][b][{full,left,right}][128]: dp folded through conv weights ----------------
__global__ void bias3_kernel(const float* __restrict__ dp, const float* __restrict__ dconv_W,
                             const float* __restrict__ dconv_b, float* __restrict__ bias3) {
    int i = blockIdx.x, b = blockIdx.y, o = threadIdx.x;  // 128 threads
    __shared__ float sdp[64];
    if (o < 64) sdp[o] = dp[(i * BB + b) * 64 + o];
    __syncthreads();
    const float* wrow = dconv_W + (size_t)(i * 128 + o) * 192;
    float f = 0.f, lft = 0.f, rgt = 0.f;
    for (int c = 0; c < 64; ++c) {
        float w0 = wrow[c * 3 + 0], w1 = wrow[c * 3 + 1], w2 = wrow[c * 3 + 2];
        float dv = sdp[c];
        f += dv * (w0 + w1 + w2);
        lft += dv * w0;
        rgt += dv * w2;
    }
    float* dst = bias3 + (size_t)(i * BB + b) * 384;
    dst[o] = f + dconv_b[i * 128 + o];
    dst[128 + o] = lft;
    dst[256 + o] = rgt;
}

// ---------------- input projection -> x[b][l][c] bf16 ----------------
__global__ void inproj_kernel(const float* __restrict__ audio, const float* __restrict__ Win,
                              const float* __restrict__ bin_, ushort* __restrict__ x) {
    int idx = blockIdx.x * 256 + threadIdx.x;  // B*L*8
    int c8 = idx & 7;
    int l = (idx >> 3) & (LL - 1);
    int b = idx >> 18;
    float a = audio[(size_t)b * LL + l];
    ushort us[8];
    #pragma unroll
    for (int cc = 0; cc < 8; ++cc) {
        int c = c8 * 8 + cc;
        float v = a * Win[c] + bin_[c];
        us[cc] = f2bf(v > 0.f ? v : 0.f);
    }
    ushort4* dst = (ushort4*)(x + ((size_t)b * LL + l) * 64 + c8 * 8);
    dst[0] = make_ushort4(us[0], us[1], us[2], us[3]);
    dst[1] = make_ushort4(us[4], us[5], us[6], us[7]);
}

// ---------------- fused residual layer (conv GEMM + gate + proj GEMM + RMW) ----------------
__global__ __launch_bounds__(256) void layer_fused(
    const ushort* __restrict__ xin, ushort* __restrict__ xout, int16_t* __restrict__ skip,
    const ushort* __restrict__ wB,    // [8][6][64][8] this layer
    const ushort* __restrict__ oB,    // [8][2][64][8] this layer
    const float* __restrict__ bias3,  // [16][3][128] this layer
    const float* __restrict__ out_b,  // [128]
    int d) {
    __shared__ __align__(16) ushort su[2][16][72];  // [buf][pos][ch], row pad to 72

    const int b = blockIdx.y;
    const int seg = blockIdx.x;  // 512-pos segment
    const int tid = threadIdx.x;
    const int lane = tid & 63;
    const int p = tid >> 6;  // wave 0..3: mtile pair (p lo, p+4 hi)
    const int n = lane & 15;
    const int kg = lane >> 4;
    const int rlo = p * 16 + kg * 4;

    bf16x8 A0[6], A1[6], P0[2], P1[2];
    #pragma unroll
    for (int s = 0; s < 6; ++s) {
        A0[s] = *(const bf16x8*)(wB + ((size_t)(p * 6 + s) * 64 + lane) * 8);
        A1[s] = *(const bf16x8*)(wB + ((size_t)((p + 4) * 6 + s) * 64 + lane) * 8);
    }
    #pragma unroll
    for (int s = 0; s < 2; ++s) {
        P0[s] = *(const bf16x8*)(oB + ((size_t)(p * 2 + s) * 64 + lane) * 8);
        P1[s] = *(const bf16x8*)(oB + ((size_t)((p + 4) * 2 + s) * 64 + lane) * 8);
    }
    const float* bb = bias3 + (size_t)b * 384;
    f32x4 bF_lo = *(const f32x4*)(bb + rlo);
    f32x4 bF_hi = *(const f32x4*)(bb + 64 + rlo);
    f32x4 bL_lo = *(const f32x4*)(bb + 128 + rlo);
    f32x4 bL_hi = *(const f32x4*)(bb + 192 + rlo);
    f32x4 bR_lo = *(const f32x4*)(bb + 256 + rlo);
    f32x4 bR_hi = *(const f32x4*)(bb + 320 + rlo);
    f32x4 obL = *(const f32x4*)(out_b + rlo);
    f32x4 obH = *(const f32x4*)(out_b + 64 + rlo);

    const ushort* xb = xin + (size_t)b * LL * 64;
    ushort* xo = xout + (size_t)b * LL * 64;
    int16_t* sb = skip + (size_t)b * LL * 64;
    const float inv_s2 = 0.70710678118654752440f;

    for (int t = 0; t < 32; ++t) {
        const int l0 = seg * 512 + t * 16;
        // ---- conv B-frags (3 dilated taps) ----
        bf16x8 Bf[6];
        #pragma unroll
        for (int tap = 0; tap < 3; ++tap) {
            int lx = l0 + n + (tap - 1) * d;
            bool v = (lx >= 0) && (lx < LL);
            #pragma unroll
            for (int h = 0; h < 2; ++h) {
                bf16x8 bv = {0, 0, 0, 0, 0, 0, 0, 0};
                if (v) bv = *(const bf16x8*)(xb + (size_t)lx * 64 + h * 32 + kg * 8);
                Bf[tap * 2 + h] = bv;
            }
        }
        // ---- GEMM1: 128 conv channels ----
        f32x4 accL = {0.f, 0.f, 0.f, 0.f}, accH = {0.f, 0.f, 0.f, 0.f};
        #pragma unroll
        for (int s = 0; s < 6; ++s) {
            accL = __builtin_amdgcn_mfma_f32_16x16x32_bf16(A0[s], Bf[s], accL, 0, 0, 0);
            accH = __builtin_amdgcn_mfma_f32_16x16x32_bf16(A1[s], Bf[s], accH, 0, 0, 0);
        }
        // ---- gate + border corrections -> u (4 ch) -> LDS ----
        int lx0 = l0 + n;
        float selL = (lx0 < d) ? 1.f : 0.f;
        float selR = (lx0 >= LL - d) ? 1.f : 0.f;
        ushort4 uq;
        #pragma unroll
        for (int j = 0; j < 4; ++j) {
            float lo = accL[j] + bF_lo[j] - selL * bL_lo[j] - selR * bR_lo[j];
            float hi = accH[j] + bF_hi[j] - selL * bL_hi[j] - selR * bR_hi[j];
            float tv = 1.f - 2.f / (1.f + __expf(2.f * lo));
            float sv = 1.f / (1.f + __expf(-hi));
            ushort q = f2bf(tv * sv);
            if (j == 0) uq.x = q;
            if (j == 1) uq.y = q;
            if (j == 2) uq.z = q;
            if (j == 3) uq.w = q;
        }
        *(ushort4*)&su[t & 1][n][rlo] = uq;
        __syncthreads();
        // ---- GEMM2: z = out_W . u ----
        bf16x8 Bp[2];
        #pragma unroll
        for (int s = 0; s < 2; ++s)
            Bp[s] = *(const bf16x8*)&su[t & 1][n][s * 32 + kg * 8];
        f32x4 zL = {0.f, 0.f, 0.f, 0.f}, zH = {0.f, 0.f, 0.f, 0.f};
        #pragma unroll
        for (int s = 0; s < 2; ++s) {
            zL = __builtin_amdgcn_mfma_f32_16x16x32_bf16(P0[s], Bp[s], zL, 0, 0, 0);
            zH = __builtin_amdgcn_mfma_f32_16x16x32_bf16(P1[s], Bp[s], zH, 0, 0, 0);
        }
        // ---- epilogue: x out-of-place update, skip RMW ----
        size_t off = (size_t)lx0 * 64 + rlo;
        ushort4 xv = *(const ushort4*)(xb + off);
        ushort4 xn;
        xn.x = f2bf((bf2f(xv.x) + zL[0] + obL[0]) * inv_s2);
        xn.y = f2bf((bf2f(xv.y) + zL[1] + obL[1]) * inv_s2);
        xn.z = f2bf((bf2f(xv.z) + zL[2] + obL[2]) * inv_s2);
        xn.w = f2bf((bf2f(xv.w) + zL[3] + obL[3]) * inv_s2);
        *(ushort4*)(xo + off) = xn;
        short4 so = *(const short4*)(sb + off);
        short4 sn;
        float v;
        v = fminf(fmaxf((float)so.x * SSI + zH[0] + obH[0], -1.999f), 1.999f);
        sn.x = (short)__float2int_rn(v * SS);
        v = fminf(fmaxf((float)so.y * SSI + zH[1] + obH[1], -1.999f), 1.999f);
        sn.y = (short)__float2int_rn(v * SS);
        v = fminf(fmaxf((float)so.z * SSI + zH[2] + obH[2], -1.999f), 1.999f);
        sn.z = (short)__float2int_rn(v * SS);
        v = fminf(fmaxf((float)so.w * SSI + zH[3] + obH[3], -1.999f), 1.999f);
        sn.w = (short)__float2int_rn(v * SS);
        *(short4*)(sb + off) = sn;
    }
}

// ---------------- output head (MFMA, exact int16 hi/lo split) ----------------
__global__ __launch_bounds__(256) void head_mfma(const int16_t* __restrict__ skip,
                                                 const ushort* __restrict__ Wo1B,  // [4][2][64][8]
                                                 const float* __restrict__ bo1,
                                                 const float* __restrict__ Wo2,
                                                 const float* __restrict__ bo2,
                                                 float* __restrict__ out) {
    const int b = blockIdx.y;
    const int seg = blockIdx.x;  // 1024-pos segment
    const int tid = threadIdx.x;
    const int lane = tid & 63;
    const int w = tid >> 6;
    const int n = lane & 15;
    const int kg = lane >> 4;

    bf16x8 A[4][2];
    #pragma unroll
    for (int mt = 0; mt < 4; ++mt)
        #pragma unroll
        for (int s = 0; s < 2; ++s)
            A[mt][s] = *(const bf16x8*)(Wo1B + ((size_t)(mt * 2 + s) * 64 + lane) * 8);
    f32x4 bo1v[4], wo2v[4];
    #pragma unroll
    for (int mt = 0; mt < 4; ++mt) {
        bo1v[mt] = *(const f32x4*)(bo1 + mt * 16 + kg * 4);
        wo2v[mt] = *(const f32x4*)(Wo2 + mt * 16 + kg * 4);
    }
    const float bo2v = bo2[0];
    const int16_t* sb = skip + (size_t)b * LL * 64;

    for (int t = 0; t < 16; ++t) {
        const int l0 = seg * 1024 + t * 64 + w * 16;
        bf16x8 BH[2], BL[2];
        #pragma unroll
        for (int s = 0; s < 2; ++s) {
            s16x8 v = *(const s16x8*)(sb + (size_t)(l0 + n) * 64 + s * 32 + kg * 8);
            bf16x8 bh, bl;
            #pragma unroll
            for (int e = 0; e < 8; ++e) {
                int sv = (int)v[e];
                int h8 = sv >> 8;           // arithmetic: floor(sv/256)
                int l8 = sv - (h8 << 8);    // in [0,255], exact in bf16
                bh[e] = (short)f2bf((float)h8);
                bl[e] = (short)f2bf((float)l8);
            }
            BH[s] = bh;
            BL[s] = bl;
        }
        f32x4 aH[4], aL[4];
        #pragma unroll
        for (int mt = 0; mt < 4; ++mt) {
            aH[mt] = (f32x4){0.f, 0.f, 0.f, 0.f};
            aL[mt] = (f32x4){0.f, 0.f, 0.f, 0.f};
            #pragma unroll
            for (int s = 0; s < 2; ++s) {
                aH[mt] = __builtin_amdgcn_mfma_f32_16x16x32_bf16(A[mt][s], BH[s], aH[mt], 0, 0, 0);
                aL[mt] = __builtin_amdgcn_mfma_f32_16x16x32_bf16(A[mt][s], BL[s], aL[mt], 0, 0, 0);
            }
        }
        float partial = 0.f;
        #pragma unroll
        for (int mt = 0; mt < 4; ++mt) {
            #pragma unroll
            for (int j = 0; j < 4; ++j) {
                float h = aH[mt][j] * 256.f + aL[mt][j] + bo1v[mt][j];
                partial += (h > 0.f ? h : 0.f) * wo2v[mt][j];
            }
        }
        partial += __shfl_xor(partial, 16, 64);
        partial += __shfl_xor(partial, 32, 64);
        if (kg == 0) out[(size_t)b * LL + l0 + n] = partial + bo2v;
    }
}

extern "C" void kernel_launch(void* const* d_in, const int* in_sizes, int n_in,
                              void* d_out, int out_size, void* d_ws, size_t ws_size,
                              hipStream_t stream) {
    const float* audio = (const float*)d_in[0];
    const int* dstep = (const int*)d_in[1];
    const float* emb = (const float*)d_in[2];
    const float* W1 = (const float*)d_in[3];
    const float* b1 = (const float*)d_in[4];
    const float* W2 = (const float*)d_in[5];
    const float* b2 = (const float*)d_in[6];
    const float* Win = (const float*)d_in[7];
    const float* bin_ = (const float*)d_in[8];
    const float* diff_W = (const float*)d_in[9];
    const float* diff_b = (const float*)d_in[10];
    const float* dconv_W = (const float*)d_in[11];
    const float* dconv_b = (const float*)d_in[12];
    const float* out_W = (const float*)d_in[13];
    const float* out_b = (const float*)d_in[14];
    const float* Wo1 = (const float*)d_in[15];
    const float* bo1 = (const float*)d_in[16];
    const float* Wo2 = (const float*)d_in[17];
    const float* bo2 = (const float*)d_in[18];

    const size_t NACT = (size_t)BB * LL * 64;  // 33,554,432 elements

    uint8_t* p = (uint8_t*)d_ws;
    ushort* x0 = (ushort*)p;     p += NACT * 2;   // bf16 [b][l][c]
    ushort* x1 = (ushort*)p;     p += NACT * 2;   // bf16 [b][l][c]
    int16_t* skip = (int16_t*)p; p += NACT * 2;   // int16 [b][l][c]
    float* t = (float*)p;        p += 8192 * 4;
    float* dp = (float*)p;       p += 30720 * 4;
    float* bias3 = (float*)p;    p += 184320 * 4;
    ushort* wB = (ushort*)p;     p += 737280 * 2;
    ushort* oB = (ushort*)p;     p += 245760 * 2;
    ushort* Wo1B = (ushort*)p;   p += 4096 * 2;

    hipMemsetAsync(skip, 0, NACT * 2, stream);
    emb_kernel<<<BB, 512, 0, stream>>>(dstep, emb, W1, b1, W2, b2, t);
    dp_kernel<<<dim3(NLAYERS, BB), 64, 0, stream>>>(t, diff_W, diff_b, dp);
    prep_w_kernel<<<2880, 256, 0, stream>>>(dconv_W, wB, out_W, oB, Wo1, Wo1B);
    bias3_kernel<<<dim3(NLAYERS, BB), 128, 0, stream>>>(dp, dconv_W, dconv_b, bias3);
    inproj_kernel<<<16384, 256, 0, stream>>>(audio, Win, bin_, x0);

    dim3 lgrid(LL / 512, BB);
    ushort* xin = x0;
    ushort* xout = x1;
    for (int i = 0; i < NLAYERS; ++i) {
        int d = 1 << (i % 10);
        layer_fused<<<lgrid, 256, 0, stream>>>(
            xin, xout, skip, wB + (size_t)i * 24576, oB + (size_t)i * 8192,
            bias3 + (size_t)i * BB * 384, out_b + i * 128, d);
        ushort* tmp = xin; xin = xout; xout = tmp;
    }
    head_mfma<<<dim3(LL / 1024, BB), 256, 0, stream>>>(skip, Wo1B, bo1, Wo2, bo2,
                                                       (float*)d_out);
}

// Round 8
// 4477.980 us; speedup vs baseline: 3.2058x; 1.1774x over previous
//
#include <hip/hip_runtime.h>
#include <hip/hip_bf16.h>
#include <math.h>
#include <stdint.h>

#define NLAYERS 30
#define BB 16
#define LL 32768
#define SEG 256
#define NT (SEG / 16)

#define SS 16384.0f
#define SSI (1.0f / 16384.0f)

typedef __attribute__((ext_vector_type(8))) short bf16x8;
typedef __attribute__((ext_vector_type(8))) short s16x8;
typedef __attribute__((ext_vector_type(4))) float f32x4;

__device__ inline float bf2f(ushort u) {
    union { uint i; float f; } v; v.i = ((uint)u) << 16; return v.f;
}
__device__ inline ushort f2bf(float f) {  // RNE
    uint u = __float_as_uint(f);
    return (ushort)((u + 0x7FFFu + ((u >> 16) & 1u)) >> 16);
}

// ---------------- embedding MLP: t[b,512] ----------------
__global__ void emb_kernel(const int* __restrict__ step, const float* __restrict__ emb,
                           const float* __restrict__ W1, const float* __restrict__ b1,
                           const float* __restrict__ W2, const float* __restrict__ b2,
                           float* __restrict__ t_out) {
    int b = blockIdx.x, j = threadIdx.x;
    __shared__ float e[128];
    __shared__ float t1[512];
    int s = step[b];
    if (j < 128) e[j] = emb[s * 128 + j];
    __syncthreads();
    float acc = b1[j];
    const float* w = W1 + j * 128;
    for (int k = 0; k < 128; ++k) acc += w[k] * e[k];
    t1[j] = acc / (1.f + __expf(-acc));
    __syncthreads();
    float acc2 = b2[j];
    const float* w2 = W2 + j * 512;
    for (int k = 0; k < 512; ++k) acc2 += w2[k] * t1[k];
    t_out[b * 512 + j] = acc2 / (1.f + __expf(-acc2));
}

// ---------------- dp[i,b,c] = t[b] . diff_W[i,c,:] + diff_b[i,c] ----------------
__global__ void dp_kernel(const float* __restrict__ t, const float* __restrict__ diff_W,
                          const float* __restrict__ diff_b, float* __restrict__ dp) {
    int i = blockIdx.x, b = blockIdx.y, c = threadIdx.x;  // 64 threads
    __shared__ float ts[512];
    for (int k = c; k < 512; k += 64) ts[k] = t[b * 512 + k];
    __syncthreads();
    const float* w = diff_W + (size_t)(i * 64 + c) * 512;
    float acc = diff_b[i * 64 + c];
    for (int k = 0; k < 512; ++k) acc += w[k] * ts[k];
    dp[(i * BB + b) * 64 + c] = acc;
}

// ---------------- weight shuffles into MFMA fragment order (bf16) ----------------
__global__ void prep_w_kernel(const float* __restrict__ dconv_W, ushort* __restrict__ wB,
                              const float* __restrict__ out_W, ushort* __restrict__ oB,
                              const float* __restrict__ Wo1, ushort* __restrict__ Wo1B) {
    int idx = blockIdx.x * 256 + threadIdx.x;
    if (idx < 30 * 8 * 6 * 512) {
        int i = idx / 24576;
        int r = idx % 24576;
        int mt = r / 3072;
        int s = (r / 512) % 6;
        int lane = (r >> 3) & 63;
        int j = r & 7;
        int o = mt * 16 + (lane & 15);
        int tap = s >> 1;
        int c = (s & 1) * 32 + (lane >> 4) * 8 + j;
        wB[idx] = f2bf(dconv_W[((size_t)(i * 128 + o) * 64 + c) * 3 + tap]);
    }
    if (idx < 30 * 8 * 2 * 512) {
        int i = idx / 8192;
        int r = idx % 8192;
        int mt = r / 1024;
        int s = (r / 512) % 2;
        int lane = (r >> 3) & 63;
        int j = r & 7;
        int o = mt * 16 + (lane & 15);
        int c = s * 32 + (lane >> 4) * 8 + j;
        oB[idx] = f2bf(out_W[(size_t)(i * 128 + o) * 64 + c]);
    }
    if (idx < 4 * 2 * 512) {
        int mt = idx / 1024;
        int s = (idx / 512) % 2;
        int lane = (idx >> 3) & 63;
        int j = idx & 7;
        int o = mt * 16 + (lane & 15);
        int c = s * 32 + (lane >> 4) * 8 + j;
        const float hscale = SSI * 0.18257418583505537115f;  // SSI / sqrt(30)
        Wo1B[idx] = f2bf(Wo1[o * 64 + c] * hscale);
    }
}

// ---------------- bias3[i][b][{full,left,right}][128] ----------------
__global__ void bias3_kernel(const float* __restrict__ dp, const float* __restrict__ dconv_W,
                             const float* __restrict__ dconv_b, float* __restrict__ bias3) {
    int i = blockIdx.x, b = blockIdx.y, o = threadIdx.x;  // 128 threads
    __shared__ float sdp[64];
    if (o < 64) sdp[o] = dp[(i * BB + b) * 64 + o];
    __syncthreads();
    const float* wrow = dconv_W + (size_t)(i * 128 + o) * 192;
    float f = 0.f, lft = 0.f, rgt = 0.f;
    for (int c = 0; c < 64; ++c) {
        float w0 = wrow[c * 3 + 0], w1 = wrow[c * 3 + 1], w2 = wrow[c * 3 + 2];
        float dv = sdp[c];
        f += dv * (w0 + w1 + w2);
        lft += dv * w0;
        rgt += dv * w2;
    }
    float* dst = bias3 + (size_t)(i * BB + b) * 384;
    dst[o] = f + dconv_b[i * 128 + o];
    dst[128 + o] = lft;
    dst[256 + o] = rgt;
}

// ---------------- input projection -> x[b][l][c] bf16 ----------------
__global__ void inproj_kernel(const float* __restrict__ audio, const float* __restrict__ Win,
                              const float* __restrict__ bin_, ushort* __restrict__ x) {
    int idx = blockIdx.x * 256 + threadIdx.x;  // B*L*8
    int c8 = idx & 7;
    int l = (idx >> 3) & (LL - 1);
    int b = idx >> 18;
    float a = audio[(size_t)b * LL + l];
    ushort us[8];
    #pragma unroll
    for (int cc = 0; cc < 8; ++cc) {
        int c = c8 * 8 + cc;
        float v = a * Win[c] + bin_[c];
        us[cc] = f2bf(v > 0.f ? v : 0.f);
    }
    ushort4* dst = (ushort4*)(x + ((size_t)b * LL + l) * 64 + c8 * 8);
    dst[0] = make_ushort4(us[0], us[1], us[2], us[3]);
    dst[1] = make_ushort4(us[4], us[5], us[6], us[7]);
}

// ---------------- fused residual layer, software-pipelined ----------------
__global__ __launch_bounds__(256) void layer_fused(
    const ushort* __restrict__ xin, ushort* __restrict__ xout, int16_t* __restrict__ skip,
    const ushort* __restrict__ wB,    // [8][6][64][8] this layer
    const ushort* __restrict__ oB,    // [8][2][64][8] this layer
    const float* __restrict__ bias3,  // [16][3][128] this layer
    const float* __restrict__ out_b,  // [128]
    int d) {
    __shared__ __align__(16) ushort su[2][16][72];

    const int b = blockIdx.y;
    const int seg = blockIdx.x;  // SEG-pos segment
    const int tid = threadIdx.x;
    const int lane = tid & 63;
    const int p = tid >> 6;
    const int n = lane & 15;
    const int kg = lane >> 4;
    const int rlo = p * 16 + kg * 4;

    bf16x8 A0[6], A1[6], P0[2], P1[2];
    #pragma unroll
    for (int s = 0; s < 6; ++s) {
        A0[s] = *(const bf16x8*)(wB + ((size_t)(p * 6 + s) * 64 + lane) * 8);
        A1[s] = *(const bf16x8*)(wB + ((size_t)((p + 4) * 6 + s) * 64 + lane) * 8);
    }
    #pragma unroll
    for (int s = 0; s < 2; ++s) {
        P0[s] = *(const bf16x8*)(oB + ((size_t)(p * 2 + s) * 64 + lane) * 8);
        P1[s] = *(const bf16x8*)(oB + ((size_t)((p + 4) * 2 + s) * 64 + lane) * 8);
    }
    const float* bb = bias3 + (size_t)b * 384;
    f32x4 bF_lo = *(const f32x4*)(bb + rlo);
    f32x4 bF_hi = *(const f32x4*)(bb + 64 + rlo);
    f32x4 bL_lo = *(const f32x4*)(bb + 128 + rlo);
    f32x4 bL_hi = *(const f32x4*)(bb + 192 + rlo);
    f32x4 bR_lo = *(const f32x4*)(bb + 256 + rlo);
    f32x4 bR_hi = *(const f32x4*)(bb + 320 + rlo);
    f32x4 obL = *(const f32x4*)(out_b + rlo);
    f32x4 obH = *(const f32x4*)(out_b + 64 + rlo);

    const ushort* xb = xin + (size_t)b * LL * 64;
    ushort* xo = xout + (size_t)b * LL * 64;
    int16_t* sb = skip + (size_t)b * LL * 64;
    const float inv_s2 = 0.70710678118654752440f;

#define LOADB(DST, TT)                                                           \
    {                                                                            \
        const int l0_ = seg * SEG + (TT) * 16;                                   \
        _Pragma("unroll")                                                        \
        for (int tap = 0; tap < 3; ++tap) {                                      \
            int lx = l0_ + n + (tap - 1) * d;                                    \
            bool v = (lx >= 0) && (lx < LL);                                     \
            _Pragma("unroll")                                                    \
            for (int h = 0; h < 2; ++h) {                                        \
                bf16x8 bv = {0, 0, 0, 0, 0, 0, 0, 0};                            \
                if (v) bv = *(const bf16x8*)(xb + (size_t)lx * 64 + h * 32 + kg * 8); \
                DST[tap * 2 + h] = bv;                                           \
            }                                                                    \
        }                                                                        \
    }

#define LOADE(XV, SO, TT)                                                        \
    {                                                                            \
        size_t off_ = (size_t)(seg * SEG + (TT) * 16 + n) * 64 + rlo;            \
        XV = *(const ushort4*)(xb + off_);                                       \
        SO = *(const short4*)(sb + off_);                                        \
    }

#define BODY(TT, BUF, BF, XV, SO)                                                \
    {                                                                            \
        f32x4 accL = {0.f, 0.f, 0.f, 0.f}, accH = {0.f, 0.f, 0.f, 0.f};          \
        _Pragma("unroll")                                                        \
        for (int s = 0; s < 6; ++s) {                                            \
            accL = __builtin_amdgcn_mfma_f32_16x16x32_bf16(A0[s], BF[s], accL, 0, 0, 0); \
            accH = __builtin_amdgcn_mfma_f32_16x16x32_bf16(A1[s], BF[s], accH, 0, 0, 0); \
        }                                                                        \
        const int lx0 = seg * SEG + (TT) * 16 + n;                               \
        float selL = (lx0 < d) ? 1.f : 0.f;                                      \
        float selR = (lx0 >= LL - d) ? 1.f : 0.f;                                \
        ushort4 uq;                                                              \
        _Pragma("unroll")                                                        \
        for (int j = 0; j < 4; ++j) {                                            \
            float lo = accL[j] + bF_lo[j] - selL * bL_lo[j] - selR * bR_lo[j];   \
            float hi = accH[j] + bF_hi[j] - selL * bL_hi[j] - selR * bR_hi[j];   \
            float tv = 1.f - 2.f / (1.f + __expf(2.f * lo));                     \
            float sv = 1.f / (1.f + __expf(-hi));                                \
            ushort q = f2bf(tv * sv);                                            \
            if (j == 0) uq.x = q;                                                \
            if (j == 1) uq.y = q;                                                \
            if (j == 2) uq.z = q;                                                \
            if (j == 3) uq.w = q;                                                \
        }                                                                        \
        *(ushort4*)&su[BUF][n][rlo] = uq;                                        \
        asm volatile("s_waitcnt lgkmcnt(0)" ::: "memory");                       \
        __builtin_amdgcn_s_barrier();                                            \
        asm volatile("" ::: "memory");                                           \
        bf16x8 Bp0 = *(const bf16x8*)&su[BUF][n][kg * 8];                        \
        bf16x8 Bp1 = *(const bf16x8*)&su[BUF][n][32 + kg * 8];                   \
        f32x4 zL = {0.f, 0.f, 0.f, 0.f}, zH = {0.f, 0.f, 0.f, 0.f};              \
        zL = __builtin_amdgcn_mfma_f32_16x16x32_bf16(P0[0], Bp0, zL, 0, 0, 0);   \
        zH = __builtin_amdgcn_mfma_f32_16x16x32_bf16(P1[0], Bp0, zH, 0, 0, 0);   \
        zL = __builtin_amdgcn_mfma_f32_16x16x32_bf16(P0[1], Bp1, zL, 0, 0, 0);   \
        zH = __builtin_amdgcn_mfma_f32_16x16x32_bf16(P1[1], Bp1, zH, 0, 0, 0);   \
        size_t off = (size_t)lx0 * 64 + rlo;                                     \
        ushort4 xn;                                                              \
        xn.x = f2bf((bf2f(XV.x) + zL[0] + obL[0]) * inv_s2);                     \
        xn.y = f2bf((bf2f(XV.y) + zL[1] + obL[1]) * inv_s2);                     \
        xn.z = f2bf((bf2f(XV.z) + zL[2] + obL[2]) * inv_s2);                     \
        xn.w = f2bf((bf2f(XV.w) + zL[3] + obL[3]) * inv_s2);                     \
        *(ushort4*)(xo + off) = xn;                                              \
        short4 sn;                                                               \
        float v;                                                                 \
        v = fminf(fmaxf((float)SO.x * SSI + zH[0] + obH[0], -1.999f), 1.999f);   \
        sn.x = (short)__float2int_rn(v * SS);                                    \
        v = fminf(fmaxf((float)SO.y * SSI + zH[1] + obH[1], -1.999f), 1.999f);   \
        sn.y = (short)__float2int_rn(v * SS);                                    \
        v = fminf(fmaxf((float)SO.z * SSI + zH[2] + obH[2], -1.999f), 1.999f);   \
        sn.z = (short)__float2int_rn(v * SS);                                    \
        v = fminf(fmaxf((float)SO.w * SSI + zH[3] + obH[3], -1.999f), 1.999f);   \
        sn.w = (short)__float2int_rn(v * SS);                                    \
        *(short4*)(sb + off) = sn;                                               \
    }

    bf16x8 FA[6], FB[6];
    ushort4 xvA, xvB;
    short4 soA, soB;
    LOADB(FA, 0)
    LOADE(xvA, soA, 0)
    for (int t = 0; t < NT; t += 2) {
        LOADB(FB, t + 1)
        LOADE(xvB, soB, t + 1)
        BODY(t, 0, FA, xvA, soA)
        const int tn = (t + 2 < NT) ? t + 2 : NT - 2;
        LOADB(FA, tn)
        LOADE(xvA, soA, tn)
        BODY(t + 1, 1, FB, xvB, soB)
    }
#undef LOADB
#undef LOADE
#undef BODY
}

// ---------------- output head (MFMA, exact int16 hi/lo split) ----------------
__global__ __launch_bounds__(256) void head_mfma(const int16_t* __restrict__ skip,
                                                 const ushort* __restrict__ Wo1B,  // [4][2][64][8]
                                                 const float* __restrict__ bo1,
                                                 const float* __restrict__ Wo2,
                                                 const float* __restrict__ bo2,
                                                 float* __restrict__ out) {
    const int b = blockIdx.y;
    const int seg = blockIdx.x;  // 1024-pos segment
    const int tid = threadIdx.x;
    const int lane = tid & 63;
    const int w = tid >> 6;
    const int n = lane & 15;
    const int kg = lane >> 4;

    bf16x8 A[4][2];
    #pragma unroll
    for (int mt = 0; mt < 4; ++mt)
        #pragma unroll
        for (int s = 0; s < 2; ++s)
            A[mt][s] = *(const bf16x8*)(Wo1B + ((size_t)(mt * 2 + s) * 64 + lane) * 8);
    f32x4 bo1v[4], wo2v[4];
    #pragma unroll
    for (int mt = 0; mt < 4; ++mt) {
        bo1v[mt] = *(const f32x4*)(bo1 + mt * 16 + kg * 4);
        wo2v[mt] = *(const f32x4*)(Wo2 + mt * 16 + kg * 4);
    }
    const float bo2v = bo2[0];
    const int16_t* sb = skip + (size_t)b * LL * 64;

    for (int t = 0; t < 16; ++t) {
        const int l0 = seg * 1024 + t * 64 + w * 16;
        bf16x8 BH[2], BL[2];
        #pragma unroll
        for (int s = 0; s < 2; ++s) {
            s16x8 v = *(const s16x8*)(sb + (size_t)(l0 + n) * 64 + s * 32 + kg * 8);
            bf16x8 bh, bl;
            #pragma unroll
            for (int e = 0; e < 8; ++e) {
                int sv = (int)v[e];
                int h8 = sv >> 8;
                int l8 = sv - (h8 << 8);
                bh[e] = (short)f2bf((float)h8);
                bl[e] = (short)f2bf((float)l8);
            }
            BH[s] = bh;
            BL[s] = bl;
        }
        f32x4 aH[4], aL[4];
        #pragma unroll
        for (int mt = 0; mt < 4; ++mt) {
            aH[mt] = (f32x4){0.f, 0.f, 0.f, 0.f};
            aL[mt] = (f32x4){0.f, 0.f, 0.f, 0.f};
            #pragma unroll
            for (int s = 0; s < 2; ++s) {
                aH[mt] = __builtin_amdgcn_mfma_f32_16x16x32_bf16(A[mt][s], BH[s], aH[mt], 0, 0, 0);
                aL[mt] = __builtin_amdgcn_mfma_f32_16x16x32_bf16(A[mt][s], BL[s], aL[mt], 0, 0, 0);
            }
        }
        float partial = 0.f;
        #pragma unroll
        for (int mt = 0; mt < 4; ++mt) {
            #pragma unroll
            for (int j = 0; j < 4; ++j) {
                float h = aH[mt][j] * 256.f + aL[mt][j] + bo1v[mt][j];
                partial += (h > 0.f ? h : 0.f) * wo2v[mt][j];
            }
        }
        partial += __shfl_xor(partial, 16, 64);
        partial += __shfl_xor(partial, 32, 64);
        if (kg == 0) out[(size_t)b * LL + l0 + n] = partial + bo2v;
    }
}

extern "C" void kernel_launch(void* const* d_in, const int* in_sizes, int n_in,
                              void* d_out, int out_size, void* d_ws, size_t ws_size,
                              hipStream_t stream) {
    const float* audio = (const float*)d_in[0];
    const int* dstep = (const int*)d_in[1];
    const float* emb = (const float*)d_in[2];
    const float* W1 = (const float*)d_in[3];
    const float* b1 = (const float*)d_in[4];
    const float* W2 = (const float*)d_in[5];
    const float* b2 = (const float*)d_in[6];
    const float* Win = (const float*)d_in[7];
    const float* bin_ = (const float*)d_in[8];
    const float* diff_W = (const float*)d_in[9];
    const float* diff_b = (const float*)d_in[10];
    const float* dconv_W = (const float*)d_in[11];
    const float* dconv_b = (const float*)d_in[12];
    const float* out_W = (const float*)d_in[13];
    const float* out_b = (const float*)d_in[14];
    const float* Wo1 = (const float*)d_in[15];
    const float* bo1 = (const float*)d_in[16];
    const float* Wo2 = (const float*)d_in[17];
    const float* bo2 = (const float*)d_in[18];

    const size_t NACT = (size_t)BB * LL * 64;

    uint8_t* p = (uint8_t*)d_ws;
    ushort* x0 = (ushort*)p;     p += NACT * 2;
    ushort* x1 = (ushort*)p;     p += NACT * 2;
    int16_t* skip = (int16_t*)p; p += NACT * 2;
    float* t = (float*)p;        p += 8192 * 4;
    float* dp = (float*)p;       p += 30720 * 4;
    float* bias3 = (float*)p;    p += 184320 * 4;
    ushort* wB = (ushort*)p;     p += 737280 * 2;
    ushort* oB = (ushort*)p;     p += 245760 * 2;
    ushort* Wo1B = (ushort*)p;   p += 4096 * 2;

    hipMemsetAsync(skip, 0, NACT * 2, stream);
    emb_kernel<<<BB, 512, 0, stream>>>(dstep, emb, W1, b1, W2, b2, t);
    dp_kernel<<<dim3(NLAYERS, BB), 64, 0, stream>>>(t, diff_W, diff_b, dp);
    prep_w_kernel<<<2880, 256, 0, stream>>>(dconv_W, wB, out_W, oB, Wo1, Wo1B);
    bias3_kernel<<<dim3(NLAYERS, BB), 128, 0, stream>>>(dp, dconv_W, dconv_b, bias3);
    inproj_kernel<<<16384, 256, 0, stream>>>(audio, Win, bin_, x0);

    dim3 lgrid(LL / SEG, BB);
    ushort* xin = x0;
    ushort* xout = x1;
    for (int i = 0; i < NLAYERS; ++i) {
        int d = 1 << (i % 10);
        layer_fused<<<lgrid, 256, 0, stream>>>(
            xin, xout, skip, wB + (size_t)i * 24576, oB + (size_t)i * 8192,
            bias3 + (size_t)i * BB * 384, out_b + i * 128, d);
        ushort* tmp = xin; xin = xout; xout = tmp;
    }
    head_mfma<<<dim3(LL / 1024, BB), 256, 0, stream>>>(skip, Wo1B, bo1, Wo2, bo2,
                                                       (float*)d_out);
}